// Round 15
// baseline (83.049 us; speedup 1.0000x reference)
//
#include <hip/hip_runtime.h>
#include <math.h>

// ---------------------------------------------------------------------------
// GAT node classifier: 2x GATConv(H=2, concat=False/head-mean) + Linear.
// FULLY FUSED, 1024 thr/block, 2 blocks/CU; one block per graph runs
// gemm1+agg1+gemm2+agg2+cls(MFMA)+ycopy in ~72.5 KB LDS; W read from L2.
// Round-15: REVERT r14's gemm load-rotate (it broke L3 reuse: FETCH 13.8->33
// MB, dur +6us). Keep r14's cls-as-MFMA, 16-col sHT zeroing, agg batch loads.
//   NaN audit: sHT node-cols 112..127 zeroed; sX/sB rows 100..111 zeroed;
//   sAs/sAd[224..255] zeroed; P cols >=100 written 0 by softmax (mult=0);
//   out2b rows 100..111 may hold NaN (sRZ stale) -> contaminates only
//   D rows 100..111 of cls, which are never stored.
// ---------------------------------------------------------------------------

#define NPG 100    // nodes per graph (fixed by problem)
#define CAP 2560   // bucket capacity per graph (mean 1700, +21 sigma)
#define EPB 4096   // edges per bucket-build block

// LDS carve (bytes); total 74176 -> launch with 74240 (72.5 KB, 2 blocks/CU)
#define OFF_HT    0        // 34816: sHT [128 chan][136 node] bf16 -> out2b [112][72] bf16
#define OFF_R3    34816    // 30464: sX/P [112][136] bf16 ; sB [112][72] bf16
#define OFF_SCNT  65280    // 6400:  scnt [100][16] u32 (4-bit multiplicities)
#define OFF_SAS   71680    // 1024:  sAs [256] f32 (tail zeroed)
#define OFF_SAD   72704    // 1024:  sAd [256] f32 (tail zeroed)
#define OFF_SRZ   73728    // 448:   sRZ [112] f32
#define SMEM_BYTES 74240

typedef __attribute__((ext_vector_type(8))) short bf16x8;
typedef __attribute__((ext_vector_type(4))) float f32x4;

__device__ __forceinline__ float lrelu(float x) { return x > 0.f ? x : 0.2f * x; }

// one instruction, 2 f32 -> packed 2 bf16 (RNE); no builtin on gfx950
__device__ __forceinline__ unsigned cvt_pk(float lo, float hi) {
    unsigned r;
    asm("v_cvt_pk_bf16_f32 %0, %1, %2" : "=v"(r) : "v"(lo), "v"(hi));
    return r;
}

__device__ __forceinline__ unsigned short f2bf(float f) {
    unsigned int u = __float_as_uint(f);
    return (unsigned short)((u + 0x7FFF + ((u >> 16) & 1)) >> 16);  // RNE
}

// Two-level bucketing: per-block LDS histogram over graphs, one global
// atomicAdd per (block,graph), then scatter staged edges to reserved ranges.
__global__ __launch_bounds__(1024) void bucket2_kernel(const int* __restrict__ src,
                                                       const int* __restrict__ dst,
                                                       int* gcnt,
                                                       unsigned short* __restrict__ bucket,
                                                       int e) {
    __shared__ int hist[512];
    __shared__ int base[512];
    __shared__ unsigned int staged[EPB];
    int tid = threadIdx.x;
    int e0 = blockIdx.x * EPB;
    int cnt = min(EPB, e - e0);

    for (int i = tid; i < 512; i += 1024) hist[i] = 0;
    __syncthreads();

    for (int i = tid; i < cnt; i += 1024) {
        int d = dst[e0 + i];
        int s = src[e0 + i];
        int g = d / NPG;
        int dloc = d - g * NPG;
        int sloc = s - g * NPG;
        staged[i] = ((unsigned)g << 16) | ((unsigned)dloc << 8) | (unsigned)sloc;
        atomicAdd(&hist[g], 1);
    }
    __syncthreads();

    if (tid < 512) {
        int h = hist[tid];
        base[tid] = h ? atomicAdd(&gcnt[tid], h) : 0;
        hist[tid] = 0;   // reuse as local cursor
    }
    __syncthreads();

    for (int i = tid; i < cnt; i += 1024) {
        unsigned v = staged[i];
        int g = v >> 16;
        int pos = base[g] + atomicAdd(&hist[g], 1);
        if (pos < CAP)
            bucket[(size_t)g * CAP + pos] = (unsigned short)(v & 0xFFFFu);
    }
}

// W1/W2/Wc f32 -> W1T [c][128], W2T [c][64], WcT [16][64] bf16 (transposed,
// WcT rows >= 10 zeroed); also zeroes gcnt.
__global__ __launch_bounds__(256) void convert_w(const float* __restrict__ W1,
                                                 const float* __restrict__ W2,
                                                 const float* __restrict__ Wc,
                                                 unsigned short* __restrict__ W1T,
                                                 unsigned short* __restrict__ W2T,
                                                 unsigned short* __restrict__ WcT,
                                                 int* gcnt, int G) {
    int stride = gridDim.x * 256;
    int t0 = blockIdx.x * 256 + threadIdx.x;
    for (int i = t0; i < 128 * 128; i += stride) {
        int k = i >> 7, c = i & 127;
        W1T[c * 128 + k] = f2bf(W1[i]);
    }
    for (int i = t0; i < 64 * 128; i += stride) {
        int k = i >> 7, c = i & 127;
        W2T[c * 64 + k] = f2bf(W2[i]);
    }
    for (int i = t0; i < 16 * 64; i += stride) {
        int j = i >> 6, k = i & 63;
        WcT[i] = (j < 10) ? f2bf(Wc[k * 10 + j]) : (unsigned short)0;
    }
    for (int i = t0; i < G; i += stride) gcnt[i] = 0;
}

// GEMM phase (16 waves): wave w<14: stripe s=w>>1 (16 rows), head-half h=w&1
// (4 col-tiles). sA [rows][SA] bf16 @ WT (GLOBAL [128 cols][K] bf16, L2) ->
// sHT[col*136+row] bf16 (packed 8B) + per-head logits into sAs/sAd.
// Simple on-demand fragment loads (r13 form — the r14 rotate broke L3 reuse).
// Fragment pattern verified on-device (rounds 8-13).
template <int K, int SA>
__device__ __forceinline__ void gemm_block(const unsigned short* sA,
                                           const unsigned short* __restrict__ WT,
                                           const float* __restrict__ a_src,
                                           const float* __restrict__ a_dst,
                                           unsigned short* sHT,
                                           float* sAs, float* sAd,
                                           int lane, int wave) {
    if (wave >= 14) return;   // 7 stripes x 2 head-halves
    int s = wave >> 1, h = wave & 1;
    int fr = lane & 15, fk = (lane >> 4) * 8;
    f32x4 acc[4];
#pragma unroll
    for (int t = 0; t < 4; ++t) acc[t] = (f32x4){0.f, 0.f, 0.f, 0.f};
#pragma unroll
    for (int ks = 0; ks < K / 32; ++ks) {
        bf16x8 a = *reinterpret_cast<const bf16x8*>(&sA[(s * 16 + fr) * SA + ks * 32 + fk]);
#pragma unroll
        for (int t = 0; t < 4; ++t) {
            bf16x8 b = *reinterpret_cast<const bf16x8*>(
                &WT[((h * 4 + t) * 16 + fr) * K + ks * 32 + fk]);
            acc[t] = __builtin_amdgcn_mfma_f32_16x16x32_bf16(a, b, acc[t], 0, 0, 0);
        }
    }
    int rb = s * 16 + (lane >> 4) * 4;
    float ps[4] = {0, 0, 0, 0}, pd[4] = {0, 0, 0, 0};
#pragma unroll
    for (int t = 0; t < 4; ++t) {
        int col = (h * 4 + t) * 16 + fr;
        float as_ = a_src[col], ad_ = a_dst[col];
        float v0 = acc[t][0], v1 = acc[t][1], v2 = acc[t][2], v3 = acc[t][3];
        ps[0] += v0 * as_; pd[0] += v0 * ad_;
        ps[1] += v1 * as_; pd[1] += v1 * ad_;
        ps[2] += v2 * as_; pd[2] += v2 * ad_;
        ps[3] += v3 * as_; pd[3] += v3 * ad_;
        *reinterpret_cast<uint2*>(&sHT[col * 136 + rb]) =
            make_uint2(cvt_pk(v0, v1), cvt_pk(v2, v3));
    }
#pragma unroll
    for (int off = 1; off <= 8; off <<= 1) {
#pragma unroll
        for (int j = 0; j < 4; ++j) {
            ps[j] += __shfl_xor(ps[j], off);
            pd[j] += __shfl_xor(pd[j], off);
        }
    }
    if (fr == 0) {
#pragma unroll
        for (int j = 0; j < 4; ++j) {
            int d = rb + j;   // up to 111; arrays sized 256
            sAs[d * 2 + h] = ps[j];
            sAd[d * 2 + h] = pd[j];
        }
    }
}

// Aggregation (16 waves, heads sequential): per head {no-max softmax (4-bit
// multiplicity, lane owns sources 2l/2l+1) -> sP packed b32; barrier; MFMA
// 28 tiles in 2 rounds (fragments batch-loaded from LDS), res += acc/z}.
__device__ __forceinline__ void agg_heads(unsigned short* sP,
                                          const unsigned short* sHT,
                                          const unsigned* scnt,
                                          const float* sAs, const float* sAd,
                                          float* sRZ, f32x4 res[2],
                                          int lane, int wave) {
    for (int head = 0; head < 2; ++head) {
        for (int d = wave; d < NPG; d += 16) {
            float adh = sAd[d * 2 + head];
            unsigned w = scnt[d * 16 + (lane >> 2)];
            int sh = (lane & 3) * 8;
            unsigned m0 = (w >> sh) & 15u;
            unsigned m1 = (w >> (sh + 4)) & 15u;
            // sAs[4l..4l+3] = {s0.h0, s0.h1, s1.h0, s1.h1}; tail (>=224) zeroed
            float4 a4 = *reinterpret_cast<const float4*>(&sAs[lane * 4]);
            float e0 = (head ? a4.y : a4.x) + adh;
            float e1 = (head ? a4.w : a4.z) + adh;
            // no max-subtraction: |e| <~6 by construction; softmax shift-inv.
            float p0 = m0 ? (float)m0 * __expf(lrelu(e0)) : 0.f;
            float p1 = m1 ? (float)m1 * __expf(lrelu(e1)) : 0.f;
            float z = p0 + p1;
            for (int off = 32; off; off >>= 1) z += __shfl_xor(z, off);
            *reinterpret_cast<unsigned*>(&sP[d * 136 + lane * 2]) = cvt_pk(p0, p1);
            if (lane == 0) sRZ[d] = 1.f / z;
        }
        __syncthreads();
#pragma unroll
        for (int i = 0; i < 2; ++i) {
            int t = wave + 16 * i;
            if (t < 28) {
                int mt = t >> 2, nt = t & 3;
                int arow = mt * 16 + (lane & 15);
                int brow = head * 64 + nt * 16 + (lane & 15);
                int kofs = (lane >> 4) * 8;
                bf16x8 pa[4], hb[4];
#pragma unroll
                for (int ks = 0; ks < 4; ++ks) {
                    pa[ks] = *reinterpret_cast<const bf16x8*>(&sP[arow * 136 + ks * 32 + kofs]);
                    hb[ks] = *reinterpret_cast<const bf16x8*>(&sHT[brow * 136 + ks * 32 + kofs]);
                }
                f32x4 acc = (f32x4){0.f, 0.f, 0.f, 0.f};
#pragma unroll
                for (int ks = 0; ks < 4; ++ks)
                    acc = __builtin_amdgcn_mfma_f32_16x16x32_bf16(pa[ks], hb[ks], acc, 0, 0, 0);
                int dbase = mt * 16 + (lane >> 4) * 4;
#pragma unroll
                for (int r = 0; r < 4; ++r)
                    res[i][r] += acc[r] * sRZ[dbase + r];
            }
        }
        __syncthreads();
    }
}

// One block (1024 thr = 16 waves) per graph: whole network in 72.5 KB LDS.
__global__ __launch_bounds__(1024, 8) void graph_fused(
    const float* __restrict__ x,
    const unsigned short* __restrict__ W1T,
    const unsigned short* __restrict__ W2T,
    const unsigned short* __restrict__ WcT,
    const float* __restrict__ as1, const float* __restrict__ ad1,
    const float* __restrict__ b1,
    const float* __restrict__ as2, const float* __restrict__ ad2,
    const float* __restrict__ b2,
    const float* __restrict__ bc,
    const int* __restrict__ gcnt, const unsigned short* __restrict__ bucket,
    const int* __restrict__ y,
    float* __restrict__ preds, float* __restrict__ yout) {
    extern __shared__ char smem[];
    unsigned short* sHT  = (unsigned short*)(smem + OFF_HT);
    unsigned short* out2b = (unsigned short*)(smem + OFF_HT); // [112][72] after agg2
    unsigned short* R3u  = (unsigned short*)(smem + OFF_R3);  // sX -> P1 -> sB -> P2
    unsigned*       scnt = (unsigned*)(smem + OFF_SCNT);
    float*          sAs  = (float*)(smem + OFF_SAS);
    float*          sAd  = (float*)(smem + OFF_SAD);
    float*          sRZ  = (float*)(smem + OFF_SRZ);

    int g = blockIdx.x, gbase = g * NPG, tid = threadIdx.x;
    int lane = tid & 63, wave = tid >> 6;
    int cnt = min(gcnt[g], CAP);
    float4 z4 = make_float4(0.f, 0.f, 0.f, 0.f);

    // ---- phase A: zero + stage ----
    for (int i = tid; i < 1600; i += 1024) scnt[i] = 0;
    for (int i = tid; i < 256; i += 1024) {                  // zero sHT node cols 112..127
        int r = i >> 1, c = 112 + (i & 1) * 8;
        *reinterpret_cast<float4*>(&sHT[r * 136 + c]) = z4;
    }
    for (int i = tid; i < NPG * 16; i += 1024) {             // x -> sX bf16
        int r = i >> 4, kc = (i & 15) * 8;
        const float* xp = &x[(size_t)(gbase + r) * 128 + kc];
        float4 v0 = *reinterpret_cast<const float4*>(xp);
        float4 v1 = *reinterpret_cast<const float4*>(xp + 4);
        uint4 u = make_uint4(cvt_pk(v0.x, v0.y), cvt_pk(v0.z, v0.w),
                             cvt_pk(v1.x, v1.y), cvt_pk(v1.z, v1.w));
        *reinterpret_cast<uint4*>(&R3u[r * 136 + kc]) = u;
    }
    for (int i = tid; i < 12 * 17; i += 1024) {              // zero sX rows 100..111
        int r = 100 + i / 17, c = (i % 17) * 8;
        *reinterpret_cast<float4*>(&R3u[r * 136 + c]) = z4;
    }
    if (tid >= 32 && tid < 64) { sAs[192 + tid] = 0.f; sAd[192 + tid] = 0.f; }  // tails 224..255
    if (tid < NPG) yout[gbase + tid] = (float)y[gbase + tid];   // fused ycopy
    __syncthreads();
    for (int i = tid; i < cnt; i += 1024) {                  // edge multiplicities
        unsigned v = bucket[(size_t)g * CAP + i];
        atomicAdd(&scnt[(v >> 8) * 16 + ((v & 255) >> 3)], 1u << ((v & 7) * 4));
    }
    __syncthreads();

    // ---- layer 1: gemm + agg ----
    gemm_block<128, 136>(R3u, W1T, as1, ad1, sHT, sAs, sAd, lane, wave);
    __syncthreads();

    f32x4 res[2];
    res[0] = (f32x4){0.f, 0.f, 0.f, 0.f};
    res[1] = (f32x4){0.f, 0.f, 0.f, 0.f};
    agg_heads(R3u, sHT, scnt, sAs, sAd, sRZ, res, lane, wave);   // P1 over sX

    // epilogue -> sB (bf16 [112][72] at R3, over dead P1): +b1, relu
    {
        unsigned short* sB = R3u;
        int fr = lane & 15;
#pragma unroll
        for (int i = 0; i < 2; ++i) {
            int t = wave + 16 * i;
            if (t < 28) {
                int mt = t >> 2, nt = t & 3;
                int col = nt * 16 + fr;
                float bv = b1[col];
                int d0 = mt * 16 + (lane >> 4) * 4;
                unsigned u01 = cvt_pk(fmaxf(0.5f * res[i][0] + bv, 0.f),
                                      fmaxf(0.5f * res[i][1] + bv, 0.f));
                unsigned u23 = cvt_pk(fmaxf(0.5f * res[i][2] + bv, 0.f),
                                      fmaxf(0.5f * res[i][3] + bv, 0.f));
                if (d0 + 0 < NPG) sB[(d0 + 0) * 72 + col] = (unsigned short)u01;
                if (d0 + 1 < NPG) sB[(d0 + 1) * 72 + col] = (unsigned short)(u01 >> 16);
                if (d0 + 2 < NPG) sB[(d0 + 2) * 72 + col] = (unsigned short)u23;
                if (d0 + 3 < NPG) sB[(d0 + 3) * 72 + col] = (unsigned short)(u23 >> 16);
            }
        }
        for (int i = tid; i < 12 * 9; i += 1024) {           // zero sB rows 100..111
            int r = 100 + i / 9, c = (i % 9) * 8;
            *reinterpret_cast<float4*>(&sB[r * 72 + c]) = z4;
        }
    }
    __syncthreads();

    // ---- layer 2: gemm + agg ----
    gemm_block<64, 72>(R3u, W2T, as2, ad2, sHT, sAs, sAd, lane, wave);
    __syncthreads();

    res[0] = (f32x4){0.f, 0.f, 0.f, 0.f};
    res[1] = (f32x4){0.f, 0.f, 0.f, 0.f};
    agg_heads(R3u, sHT, scnt, sAs, sAd, sRZ, res, lane, wave);   // P2 over sB

    // epilogue -> out2b (bf16 [112][72] over dead sHT): +b2, no relu.
    // Unguarded rows 100..111 may hold NaN (stale sRZ) -> only poisons cls
    // D rows 100..111, which are never stored.
    {
        int fr = lane & 15;
#pragma unroll
        for (int i = 0; i < 2; ++i) {
            int t = wave + 16 * i;
            if (t < 28) {
                int mt = t >> 2, nt = t & 3;
                int col = nt * 16 + fr;
                float bv = b2[col];
                int d0 = mt * 16 + (lane >> 4) * 4;
                unsigned u01 = cvt_pk(0.5f * res[i][0] + bv, 0.5f * res[i][1] + bv);
                unsigned u23 = cvt_pk(0.5f * res[i][2] + bv, 0.5f * res[i][3] + bv);
                out2b[(d0 + 0) * 72 + col] = (unsigned short)u01;
                out2b[(d0 + 1) * 72 + col] = (unsigned short)(u01 >> 16);
                out2b[(d0 + 2) * 72 + col] = (unsigned short)u23;
                out2b[(d0 + 3) * 72 + col] = (unsigned short)(u23 >> 16);
            }
        }
    }
    __syncthreads();

    // ---- classifier via MFMA: D[112x16] = out2b[112x64] @ WcT^T ----
    if (wave < 7) {
        int fr = lane & 15, fk = (lane >> 4) * 8;
        const unsigned short* ap = out2b + (wave * 16 + fr) * 72 + fk;
        const unsigned short* bp = WcT + fr * 64 + fk;
        bf16x8 a0 = *reinterpret_cast<const bf16x8*>(ap);
        bf16x8 b0 = *reinterpret_cast<const bf16x8*>(bp);
        bf16x8 a1 = *reinterpret_cast<const bf16x8*>(ap + 32);
        bf16x8 b1 = *reinterpret_cast<const bf16x8*>(bp + 32);
        f32x4 acc = (f32x4){0.f, 0.f, 0.f, 0.f};
        acc = __builtin_amdgcn_mfma_f32_16x16x32_bf16(a0, b0, acc, 0, 0, 0);
        acc = __builtin_amdgcn_mfma_f32_16x16x32_bf16(a1, b1, acc, 0, 0, 0);
        if (fr < 10) {
            float bcv = bc[fr];
            int d0 = wave * 16 + (lane >> 4) * 4;
#pragma unroll
            for (int r = 0; r < 4; ++r) {
                int d = d0 + r;
                if (d < NPG) preds[(size_t)(gbase + d) * 10 + fr] = acc[r] + bcv;
            }
        }
    }
}

extern "C" void kernel_launch(void* const* d_in, const int* in_sizes, int n_in,
                              void* d_out, int out_size, void* d_ws, size_t ws_size,
                              hipStream_t stream) {
    const float* x   = (const float*)d_in[0];
    const int*   ei  = (const int*)d_in[1];
    const int*   y   = (const int*)d_in[3];
    const float* W1  = (const float*)d_in[4];
    const float* as1 = (const float*)d_in[5];
    const float* ad1 = (const float*)d_in[6];
    const float* b1  = (const float*)d_in[7];
    const float* W2  = (const float*)d_in[8];
    const float* as2 = (const float*)d_in[9];
    const float* ad2 = (const float*)d_in[10];
    const float* b2  = (const float*)d_in[11];
    const float* Wc  = (const float*)d_in[12];
    const float* bc  = (const float*)d_in[13];

    int n = in_sizes[0] / 128;   // 50000
    int e = in_sizes[1] / 2;     // 850000
    int G = n / NPG;             // 500 graphs
    const int* src = ei;
    const int* dst = ei + e;

    char* ws = (char*)d_ws;
    size_t off = 0;
    auto alloc = [&](size_t bytes) -> void* {
        void* p = ws + off;
        off = (off + bytes + 255) & ~size_t(255);
        return p;
    };
    unsigned short* W1T = (unsigned short*)alloc((size_t)128 * 128 * 2);
    unsigned short* W2T = (unsigned short*)alloc((size_t)128 * 64 * 2);
    unsigned short* WcT = (unsigned short*)alloc((size_t)16 * 64 * 2);
    int* gcnt = (int*)alloc((size_t)G * 4);
    unsigned short* bucket = (unsigned short*)alloc((size_t)G * CAP * 2);

    float* preds = (float*)d_out;
    float* yout  = preds + (size_t)n * 10;

    int bb = (e + EPB - 1) / EPB;

    // prep: weight convert + gcnt zero, then edge bucketing
    convert_w<<<96, 256, 0, stream>>>(W1, W2, Wc, W1T, W2T, WcT, gcnt, G);
    bucket2_kernel<<<bb, 1024, 0, stream>>>(src, dst, gcnt, bucket, e);

    // the whole network, one block per graph (2 blocks/CU, 32 waves/CU)
    graph_fused<<<G, 1024, SMEM_BYTES, stream>>>(x, W1T, W2T, WcT,
                                                 as1, ad1, b1, as2, ad2, b2,
                                                 bc, gcnt, bucket, y, preds, yout);
}

// Round 16
// 81.965 us; speedup vs baseline: 1.0132x; 1.0132x over previous
//
#include <hip/hip_runtime.h>
#include <math.h>

// ---------------------------------------------------------------------------
// GAT node classifier: 2x GATConv(H=2, concat=False/head-mean) + Linear.
// FULLY FUSED, 1024 thr/block, 2 blocks/CU; one block per graph runs
// gemm1+agg1+gemm2+agg2+cls(MFMA)+ycopy in ~72.5 KB LDS; W read from L2.
// Round-16: cls result staged in LDS (dead P2 region) then stored with ONE
// coalesced linear copy. r14/r15's direct MFMA-epilogue stores were 4B @
// 40B-stride -> 3x write amplification (WRITE 5.6->16 MB) + RMW line
// fetches (FETCH +6 MB). Everything else = r15 (r13 gemm form, cls MFMA,
// 16-col sHT zeroing, agg batch loads).
//   NaN audit: sHT node-cols 112..127 zeroed; sX/sB rows 100..111 zeroed;
//   sAs/sAd[224..255] zeroed; P cols >=100 written 0 by softmax (mult=0);
//   out2b rows 100..111 may hold NaN (stale sRZ) -> contaminates only cls
//   D rows 100..111, which are never stored to sPred/global.
// ---------------------------------------------------------------------------

#define NPG 100    // nodes per graph (fixed by problem)
#define CAP 2560   // bucket capacity per graph (mean 1700, +21 sigma)
#define EPB 4096   // edges per bucket-build block

// LDS carve (bytes); total 74176 -> launch with 74240 (72.5 KB, 2 blocks/CU)
#define OFF_HT    0        // 34816: sHT [128 chan][136 node] bf16 -> out2b [112][72] bf16
#define OFF_R3    34816    // 30464: sX/P [112][136] bf16 ; sB [112][72] bf16 ; sPred [112][10] f32
#define OFF_SCNT  65280    // 6400:  scnt [100][16] u32 (4-bit multiplicities)
#define OFF_SAS   71680    // 1024:  sAs [256] f32 (tail zeroed)
#define OFF_SAD   72704    // 1024:  sAd [256] f32 (tail zeroed)
#define OFF_SRZ   73728    // 448:   sRZ [112] f32
#define SMEM_BYTES 74240

typedef __attribute__((ext_vector_type(8))) short bf16x8;
typedef __attribute__((ext_vector_type(4))) float f32x4;

__device__ __forceinline__ float lrelu(float x) { return x > 0.f ? x : 0.2f * x; }

// one instruction, 2 f32 -> packed 2 bf16 (RNE); no builtin on gfx950
__device__ __forceinline__ unsigned cvt_pk(float lo, float hi) {
    unsigned r;
    asm("v_cvt_pk_bf16_f32 %0, %1, %2" : "=v"(r) : "v"(lo), "v"(hi));
    return r;
}

__device__ __forceinline__ unsigned short f2bf(float f) {
    unsigned int u = __float_as_uint(f);
    return (unsigned short)((u + 0x7FFF + ((u >> 16) & 1)) >> 16);  // RNE
}

// Two-level bucketing: per-block LDS histogram over graphs, one global
// atomicAdd per (block,graph), then scatter staged edges to reserved ranges.
__global__ __launch_bounds__(1024) void bucket2_kernel(const int* __restrict__ src,
                                                       const int* __restrict__ dst,
                                                       int* gcnt,
                                                       unsigned short* __restrict__ bucket,
                                                       int e) {
    __shared__ int hist[512];
    __shared__ int base[512];
    __shared__ unsigned int staged[EPB];
    int tid = threadIdx.x;
    int e0 = blockIdx.x * EPB;
    int cnt = min(EPB, e - e0);

    for (int i = tid; i < 512; i += 1024) hist[i] = 0;
    __syncthreads();

    for (int i = tid; i < cnt; i += 1024) {
        int d = dst[e0 + i];
        int s = src[e0 + i];
        int g = d / NPG;
        int dloc = d - g * NPG;
        int sloc = s - g * NPG;
        staged[i] = ((unsigned)g << 16) | ((unsigned)dloc << 8) | (unsigned)sloc;
        atomicAdd(&hist[g], 1);
    }
    __syncthreads();

    if (tid < 512) {
        int h = hist[tid];
        base[tid] = h ? atomicAdd(&gcnt[tid], h) : 0;
        hist[tid] = 0;   // reuse as local cursor
    }
    __syncthreads();

    for (int i = tid; i < cnt; i += 1024) {
        unsigned v = staged[i];
        int g = v >> 16;
        int pos = base[g] + atomicAdd(&hist[g], 1);
        if (pos < CAP)
            bucket[(size_t)g * CAP + pos] = (unsigned short)(v & 0xFFFFu);
    }
}

// W1/W2/Wc f32 -> W1T [c][128], W2T [c][64], WcT [16][64] bf16 (transposed,
// WcT rows >= 10 zeroed); also zeroes gcnt.
__global__ __launch_bounds__(256) void convert_w(const float* __restrict__ W1,
                                                 const float* __restrict__ W2,
                                                 const float* __restrict__ Wc,
                                                 unsigned short* __restrict__ W1T,
                                                 unsigned short* __restrict__ W2T,
                                                 unsigned short* __restrict__ WcT,
                                                 int* gcnt, int G) {
    int stride = gridDim.x * 256;
    int t0 = blockIdx.x * 256 + threadIdx.x;
    for (int i = t0; i < 128 * 128; i += stride) {
        int k = i >> 7, c = i & 127;
        W1T[c * 128 + k] = f2bf(W1[i]);
    }
    for (int i = t0; i < 64 * 128; i += stride) {
        int k = i >> 7, c = i & 127;
        W2T[c * 64 + k] = f2bf(W2[i]);
    }
    for (int i = t0; i < 16 * 64; i += stride) {
        int j = i >> 6, k = i & 63;
        WcT[i] = (j < 10) ? f2bf(Wc[k * 10 + j]) : (unsigned short)0;
    }
    for (int i = t0; i < G; i += stride) gcnt[i] = 0;
}

// GEMM phase (16 waves): wave w<14: stripe s=w>>1 (16 rows), head-half h=w&1
// (4 col-tiles). sA [rows][SA] bf16 @ WT (GLOBAL [128 cols][K] bf16, L2) ->
// sHT[col*136+row] bf16 (packed 8B) + per-head logits into sAs/sAd.
// Simple on-demand fragment loads (r14's rotate broke L3 reuse).
// Fragment pattern verified on-device (rounds 8-15).
template <int K, int SA>
__device__ __forceinline__ void gemm_block(const unsigned short* sA,
                                           const unsigned short* __restrict__ WT,
                                           const float* __restrict__ a_src,
                                           const float* __restrict__ a_dst,
                                           unsigned short* sHT,
                                           float* sAs, float* sAd,
                                           int lane, int wave) {
    if (wave >= 14) return;   // 7 stripes x 2 head-halves
    int s = wave >> 1, h = wave & 1;
    int fr = lane & 15, fk = (lane >> 4) * 8;
    f32x4 acc[4];
#pragma unroll
    for (int t = 0; t < 4; ++t) acc[t] = (f32x4){0.f, 0.f, 0.f, 0.f};
#pragma unroll
    for (int ks = 0; ks < K / 32; ++ks) {
        bf16x8 a = *reinterpret_cast<const bf16x8*>(&sA[(s * 16 + fr) * SA + ks * 32 + fk]);
#pragma unroll
        for (int t = 0; t < 4; ++t) {
            bf16x8 b = *reinterpret_cast<const bf16x8*>(
                &WT[((h * 4 + t) * 16 + fr) * K + ks * 32 + fk]);
            acc[t] = __builtin_amdgcn_mfma_f32_16x16x32_bf16(a, b, acc[t], 0, 0, 0);
        }
    }
    int rb = s * 16 + (lane >> 4) * 4;
    float ps[4] = {0, 0, 0, 0}, pd[4] = {0, 0, 0, 0};
#pragma unroll
    for (int t = 0; t < 4; ++t) {
        int col = (h * 4 + t) * 16 + fr;
        float as_ = a_src[col], ad_ = a_dst[col];
        float v0 = acc[t][0], v1 = acc[t][1], v2 = acc[t][2], v3 = acc[t][3];
        ps[0] += v0 * as_; pd[0] += v0 * ad_;
        ps[1] += v1 * as_; pd[1] += v1 * ad_;
        ps[2] += v2 * as_; pd[2] += v2 * ad_;
        ps[3] += v3 * as_; pd[3] += v3 * ad_;
        *reinterpret_cast<uint2*>(&sHT[col * 136 + rb]) =
            make_uint2(cvt_pk(v0, v1), cvt_pk(v2, v3));
    }
#pragma unroll
    for (int off = 1; off <= 8; off <<= 1) {
#pragma unroll
        for (int j = 0; j < 4; ++j) {
            ps[j] += __shfl_xor(ps[j], off);
            pd[j] += __shfl_xor(pd[j], off);
        }
    }
    if (fr == 0) {
#pragma unroll
        for (int j = 0; j < 4; ++j) {
            int d = rb + j;   // up to 111; arrays sized 256
            sAs[d * 2 + h] = ps[j];
            sAd[d * 2 + h] = pd[j];
        }
    }
}

// Aggregation (16 waves, heads sequential): per head {no-max softmax (4-bit
// multiplicity, lane owns sources 2l/2l+1) -> sP packed b32; barrier; MFMA
// 28 tiles in 2 rounds (fragments batch-loaded from LDS), res += acc/z}.
__device__ __forceinline__ void agg_heads(unsigned short* sP,
                                          const unsigned short* sHT,
                                          const unsigned* scnt,
                                          const float* sAs, const float* sAd,
                                          float* sRZ, f32x4 res[2],
                                          int lane, int wave) {
    for (int head = 0; head < 2; ++head) {
        for (int d = wave; d < NPG; d += 16) {
            float adh = sAd[d * 2 + head];
            unsigned w = scnt[d * 16 + (lane >> 2)];
            int sh = (lane & 3) * 8;
            unsigned m0 = (w >> sh) & 15u;
            unsigned m1 = (w >> (sh + 4)) & 15u;
            // sAs[4l..4l+3] = {s0.h0, s0.h1, s1.h0, s1.h1}; tail (>=224) zeroed
            float4 a4 = *reinterpret_cast<const float4*>(&sAs[lane * 4]);
            float e0 = (head ? a4.y : a4.x) + adh;
            float e1 = (head ? a4.w : a4.z) + adh;
            // no max-subtraction: |e| <~6 by construction; softmax shift-inv.
            float p0 = m0 ? (float)m0 * __expf(lrelu(e0)) : 0.f;
            float p1 = m1 ? (float)m1 * __expf(lrelu(e1)) : 0.f;
            float z = p0 + p1;
            for (int off = 32; off; off >>= 1) z += __shfl_xor(z, off);
            *reinterpret_cast<unsigned*>(&sP[d * 136 + lane * 2]) = cvt_pk(p0, p1);
            if (lane == 0) sRZ[d] = 1.f / z;
        }
        __syncthreads();
#pragma unroll
        for (int i = 0; i < 2; ++i) {
            int t = wave + 16 * i;
            if (t < 28) {
                int mt = t >> 2, nt = t & 3;
                int arow = mt * 16 + (lane & 15);
                int brow = head * 64 + nt * 16 + (lane & 15);
                int kofs = (lane >> 4) * 8;
                bf16x8 pa[4], hb[4];
#pragma unroll
                for (int ks = 0; ks < 4; ++ks) {
                    pa[ks] = *reinterpret_cast<const bf16x8*>(&sP[arow * 136 + ks * 32 + kofs]);
                    hb[ks] = *reinterpret_cast<const bf16x8*>(&sHT[brow * 136 + ks * 32 + kofs]);
                }
                f32x4 acc = (f32x4){0.f, 0.f, 0.f, 0.f};
#pragma unroll
                for (int ks = 0; ks < 4; ++ks)
                    acc = __builtin_amdgcn_mfma_f32_16x16x32_bf16(pa[ks], hb[ks], acc, 0, 0, 0);
                int dbase = mt * 16 + (lane >> 4) * 4;
#pragma unroll
                for (int r = 0; r < 4; ++r)
                    res[i][r] += acc[r] * sRZ[dbase + r];
            }
        }
        __syncthreads();
    }
}

// One block (1024 thr = 16 waves) per graph: whole network in 72.5 KB LDS.
__global__ __launch_bounds__(1024, 8) void graph_fused(
    const float* __restrict__ x,
    const unsigned short* __restrict__ W1T,
    const unsigned short* __restrict__ W2T,
    const unsigned short* __restrict__ WcT,
    const float* __restrict__ as1, const float* __restrict__ ad1,
    const float* __restrict__ b1,
    const float* __restrict__ as2, const float* __restrict__ ad2,
    const float* __restrict__ b2,
    const float* __restrict__ bc,
    const int* __restrict__ gcnt, const unsigned short* __restrict__ bucket,
    const int* __restrict__ y,
    float* __restrict__ preds, float* __restrict__ yout) {
    extern __shared__ char smem[];
    unsigned short* sHT  = (unsigned short*)(smem + OFF_HT);
    unsigned short* out2b = (unsigned short*)(smem + OFF_HT); // [112][72] after agg2
    unsigned short* R3u  = (unsigned short*)(smem + OFF_R3);  // sX -> P1 -> sB -> P2
    float*          sPred = (float*)(smem + OFF_R3);          // [112][10] after cls
    unsigned*       scnt = (unsigned*)(smem + OFF_SCNT);
    float*          sAs  = (float*)(smem + OFF_SAS);
    float*          sAd  = (float*)(smem + OFF_SAD);
    float*          sRZ  = (float*)(smem + OFF_SRZ);

    int g = blockIdx.x, gbase = g * NPG, tid = threadIdx.x;
    int lane = tid & 63, wave = tid >> 6;
    int cnt = min(gcnt[g], CAP);
    float4 z4 = make_float4(0.f, 0.f, 0.f, 0.f);

    // ---- phase A: zero + stage ----
    for (int i = tid; i < 1600; i += 1024) scnt[i] = 0;
    for (int i = tid; i < 256; i += 1024) {                  // zero sHT node cols 112..127
        int r = i >> 1, c = 112 + (i & 1) * 8;
        *reinterpret_cast<float4*>(&sHT[r * 136 + c]) = z4;
    }
    for (int i = tid; i < NPG * 16; i += 1024) {             // x -> sX bf16
        int r = i >> 4, kc = (i & 15) * 8;
        const float* xp = &x[(size_t)(gbase + r) * 128 + kc];
        float4 v0 = *reinterpret_cast<const float4*>(xp);
        float4 v1 = *reinterpret_cast<const float4*>(xp + 4);
        uint4 u = make_uint4(cvt_pk(v0.x, v0.y), cvt_pk(v0.z, v0.w),
                             cvt_pk(v1.x, v1.y), cvt_pk(v1.z, v1.w));
        *reinterpret_cast<uint4*>(&R3u[r * 136 + kc]) = u;
    }
    for (int i = tid; i < 12 * 17; i += 1024) {              // zero sX rows 100..111
        int r = 100 + i / 17, c = (i % 17) * 8;
        *reinterpret_cast<float4*>(&R3u[r * 136 + c]) = z4;
    }
    if (tid >= 32 && tid < 64) { sAs[192 + tid] = 0.f; sAd[192 + tid] = 0.f; }  // tails 224..255
    if (tid < NPG) yout[gbase + tid] = (float)y[gbase + tid];   // fused ycopy
    __syncthreads();
    for (int i = tid; i < cnt; i += 1024) {                  // edge multiplicities
        unsigned v = bucket[(size_t)g * CAP + i];
        atomicAdd(&scnt[(v >> 8) * 16 + ((v & 255) >> 3)], 1u << ((v & 7) * 4));
    }
    __syncthreads();

    // ---- layer 1: gemm + agg ----
    gemm_block<128, 136>(R3u, W1T, as1, ad1, sHT, sAs, sAd, lane, wave);
    __syncthreads();

    f32x4 res[2];
    res[0] = (f32x4){0.f, 0.f, 0.f, 0.f};
    res[1] = (f32x4){0.f, 0.f, 0.f, 0.f};
    agg_heads(R3u, sHT, scnt, sAs, sAd, sRZ, res, lane, wave);   // P1 over sX

    // epilogue -> sB (bf16 [112][72] at R3, over dead P1): +b1, relu
    {
        unsigned short* sB = R3u;
        int fr = lane & 15;
#pragma unroll
        for (int i = 0; i < 2; ++i) {
            int t = wave + 16 * i;
            if (t < 28) {
                int mt = t >> 2, nt = t & 3;
                int col = nt * 16 + fr;
                float bv = b1[col];
                int d0 = mt * 16 + (lane >> 4) * 4;
                unsigned u01 = cvt_pk(fmaxf(0.5f * res[i][0] + bv, 0.f),
                                      fmaxf(0.5f * res[i][1] + bv, 0.f));
                unsigned u23 = cvt_pk(fmaxf(0.5f * res[i][2] + bv, 0.f),
                                      fmaxf(0.5f * res[i][3] + bv, 0.f));
                if (d0 + 0 < NPG) sB[(d0 + 0) * 72 + col] = (unsigned short)u01;
                if (d0 + 1 < NPG) sB[(d0 + 1) * 72 + col] = (unsigned short)(u01 >> 16);
                if (d0 + 2 < NPG) sB[(d0 + 2) * 72 + col] = (unsigned short)u23;
                if (d0 + 3 < NPG) sB[(d0 + 3) * 72 + col] = (unsigned short)(u23 >> 16);
            }
        }
        for (int i = tid; i < 12 * 9; i += 1024) {           // zero sB rows 100..111
            int r = 100 + i / 9, c = (i % 9) * 8;
            *reinterpret_cast<float4*>(&sB[r * 72 + c]) = z4;
        }
    }
    __syncthreads();

    // ---- layer 2: gemm + agg ----
    gemm_block<64, 72>(R3u, W2T, as2, ad2, sHT, sAs, sAd, lane, wave);
    __syncthreads();

    res[0] = (f32x4){0.f, 0.f, 0.f, 0.f};
    res[1] = (f32x4){0.f, 0.f, 0.f, 0.f};
    agg_heads(R3u, sHT, scnt, sAs, sAd, sRZ, res, lane, wave);   // P2 over sB

    // epilogue -> out2b (bf16 [112][72] over dead sHT): +b2, no relu.
    // Unguarded rows 100..111 may hold NaN (stale sRZ) -> only poisons cls
    // D rows 100..111, which are never stored.
    {
        int fr = lane & 15;
#pragma unroll
        for (int i = 0; i < 2; ++i) {
            int t = wave + 16 * i;
            if (t < 28) {
                int mt = t >> 2, nt = t & 3;
                int col = nt * 16 + fr;
                float bv = b2[col];
                int d0 = mt * 16 + (lane >> 4) * 4;
                unsigned u01 = cvt_pk(0.5f * res[i][0] + bv, 0.5f * res[i][1] + bv);
                unsigned u23 = cvt_pk(0.5f * res[i][2] + bv, 0.5f * res[i][3] + bv);
                out2b[(d0 + 0) * 72 + col] = (unsigned short)u01;
                out2b[(d0 + 1) * 72 + col] = (unsigned short)(u01 >> 16);
                out2b[(d0 + 2) * 72 + col] = (unsigned short)u23;
                out2b[(d0 + 3) * 72 + col] = (unsigned short)(u23 >> 16);
            }
        }
    }
    __syncthreads();

    // ---- classifier via MFMA -> sPred (LDS, dead P2 region) ----
    if (wave < 7) {
        int fr = lane & 15, fk = (lane >> 4) * 8;
        const unsigned short* ap = out2b + (wave * 16 + fr) * 72 + fk;
        const unsigned short* bp = WcT + fr * 64 + fk;
        bf16x8 a0 = *reinterpret_cast<const bf16x8*>(ap);
        bf16x8 b0 = *reinterpret_cast<const bf16x8*>(bp);
        bf16x8 a1 = *reinterpret_cast<const bf16x8*>(ap + 32);
        bf16x8 b1 = *reinterpret_cast<const bf16x8*>(bp + 32);
        f32x4 acc = (f32x4){0.f, 0.f, 0.f, 0.f};
        acc = __builtin_amdgcn_mfma_f32_16x16x32_bf16(a0, b0, acc, 0, 0, 0);
        acc = __builtin_amdgcn_mfma_f32_16x16x32_bf16(a1, b1, acc, 0, 0, 0);
        if (fr < 10) {
            float bcv = bc[fr];
            int d0 = wave * 16 + (lane >> 4) * 4;
#pragma unroll
            for (int r = 0; r < 4; ++r) {
                int d = d0 + r;
                if (d < NPG) sPred[d * 10 + fr] = acc[r] + bcv;
            }
        }
    }
    __syncthreads();

    // coalesced store: per-graph preds are contiguous (g*1000 .. g*1000+999)
    for (int i = tid; i < NPG * 10; i += 1024)
        preds[(size_t)gbase * 10 + i] = sPred[i];
}

extern "C" void kernel_launch(void* const* d_in, const int* in_sizes, int n_in,
                              void* d_out, int out_size, void* d_ws, size_t ws_size,
                              hipStream_t stream) {
    const float* x   = (const float*)d_in[0];
    const int*   ei  = (const int*)d_in[1];
    const int*   y   = (const int*)d_in[3];
    const float* W1  = (const float*)d_in[4];
    const float* as1 = (const float*)d_in[5];
    const float* ad1 = (const float*)d_in[6];
    const float* b1  = (const float*)d_in[7];
    const float* W2  = (const float*)d_in[8];
    const float* as2 = (const float*)d_in[9];
    const float* ad2 = (const float*)d_in[10];
    const float* b2  = (const float*)d_in[11];
    const float* Wc  = (const float*)d_in[12];
    const float* bc  = (const float*)d_in[13];

    int n = in_sizes[0] / 128;   // 50000
    int e = in_sizes[1] / 2;     // 850000
    int G = n / NPG;             // 500 graphs
    const int* src = ei;
    const int* dst = ei + e;

    char* ws = (char*)d_ws;
    size_t off = 0;
    auto alloc = [&](size_t bytes) -> void* {
        void* p = ws + off;
        off = (off + bytes + 255) & ~size_t(255);
        return p;
    };
    unsigned short* W1T = (unsigned short*)alloc((size_t)128 * 128 * 2);
    unsigned short* W2T = (unsigned short*)alloc((size_t)128 * 64 * 2);
    unsigned short* WcT = (unsigned short*)alloc((size_t)16 * 64 * 2);
    int* gcnt = (int*)alloc((size_t)G * 4);
    unsigned short* bucket = (unsigned short*)alloc((size_t)G * CAP * 2);

    float* preds = (float*)d_out;
    float* yout  = preds + (size_t)n * 10;

    int bb = (e + EPB - 1) / EPB;

    // prep: weight convert + gcnt zero, then edge bucketing
    convert_w<<<96, 256, 0, stream>>>(W1, W2, Wc, W1T, W2T, WcT, gcnt, G);
    bucket2_kernel<<<bb, 1024, 0, stream>>>(src, dst, gcnt, bucket, e);

    // the whole network, one block per graph (2 blocks/CU, 32 waves/CU)
    graph_fused<<<G, 1024, SMEM_BYTES, stream>>>(x, W1T, W2T, WcT,
                                                 as1, ad1, b1, as2, ad2, b2,
                                                 bc, gcnt, bucket, y, preds, yout);
}

// Round 17
// 78.844 us; speedup vs baseline: 1.0533x; 1.0396x over previous
//
#include <hip/hip_runtime.h>
#include <math.h>

// ---------------------------------------------------------------------------
// GAT node classifier: 2x GATConv(H=2, concat=False/head-mean) + Linear.
// FULLY FUSED, 1024 thr/block, 2 blocks/CU: one block per graph runs
// gemm1+agg1+gemm2+agg2+cls+ycopy in ~75 KB LDS; W read from L2.
// (Round-17 = exact restore of the round-13 best-known configuration:
//  78.8 us total. The r14-r16 cls-MFMA arc measured 82-83 us with 3x
//  write amplification and was abandoned.)
//   - softmax WITHOUT max-subtraction (logits bounded |e|<~6; shift-invariant)
//   - lane handles sources (2l, 2l+1): one scnt dword + one float4 sAs read
//     covers both sources x both heads; P written as packed b32 (cvt_pk).
//   - v_cvt_pk_bf16_f32 inline asm for all f32->bf16 packing.
//   - cls scalar with float4 LDS reads, contiguous global stores.
//   NaN audit: sHT zeroed; sX/sB rows 100..111 zeroed; sAs/sAd[224..255]
//   zeroed; p guarded by mult?:0; stale P rows >=100 finite -> only
//   unstored D-rows; sRZ>=100 unused.
// ---------------------------------------------------------------------------

#define NPG 100    // nodes per graph (fixed by problem)
#define CAP 2560   // bucket capacity per graph (mean 1700, +21 sigma)
#define EPB 4096   // edges per bucket-build block

// LDS carve (bytes); total 76776 -> launch with 76800 (75 KB, 2 blocks/CU)
#define OFF_HT    0        // 34816: sHT [128 chan][136 node] bf16 -> sOut [112][68] f32
#define OFF_R3    34816    // 30464: sX/P [112][136] bf16 ; sB [112][72] bf16
#define OFF_SCNT  65280    // 6400:  scnt [100][16] u32 (4-bit multiplicities)
#define OFF_SAS   71680    // 1024:  sAs [256] f32 (tail zeroed)
#define OFF_SAD   72704    // 1024:  sAd [256] f32 (tail zeroed)
#define OFF_SRZ   73728    // 448:   sRZ [112] f32
#define OFF_SWC   74176    // 2560:  sWc [640] f32
#define OFF_SBC   76736    // 40:    sbc [10] f32
#define SMEM_BYTES 76800

typedef __attribute__((ext_vector_type(8))) short bf16x8;
typedef __attribute__((ext_vector_type(4))) float f32x4;

__device__ __forceinline__ float lrelu(float x) { return x > 0.f ? x : 0.2f * x; }

// one instruction, 2 f32 -> packed 2 bf16 (RNE); no builtin on gfx950
__device__ __forceinline__ unsigned cvt_pk(float lo, float hi) {
    unsigned r;
    asm("v_cvt_pk_bf16_f32 %0, %1, %2" : "=v"(r) : "v"(lo), "v"(hi));
    return r;
}

__device__ __forceinline__ unsigned short f2bf(float f) {
    unsigned int u = __float_as_uint(f);
    return (unsigned short)((u + 0x7FFF + ((u >> 16) & 1)) >> 16);  // RNE
}

// Two-level bucketing: per-block LDS histogram over graphs, one global
// atomicAdd per (block,graph), then scatter staged edges to reserved ranges.
__global__ __launch_bounds__(1024) void bucket2_kernel(const int* __restrict__ src,
                                                       const int* __restrict__ dst,
                                                       int* gcnt,
                                                       unsigned short* __restrict__ bucket,
                                                       int e) {
    __shared__ int hist[512];
    __shared__ int base[512];
    __shared__ unsigned int staged[EPB];
    int tid = threadIdx.x;
    int e0 = blockIdx.x * EPB;
    int cnt = min(EPB, e - e0);

    for (int i = tid; i < 512; i += 1024) hist[i] = 0;
    __syncthreads();

    for (int i = tid; i < cnt; i += 1024) {
        int d = dst[e0 + i];
        int s = src[e0 + i];
        int g = d / NPG;
        int dloc = d - g * NPG;
        int sloc = s - g * NPG;
        staged[i] = ((unsigned)g << 16) | ((unsigned)dloc << 8) | (unsigned)sloc;
        atomicAdd(&hist[g], 1);
    }
    __syncthreads();

    if (tid < 512) {
        int h = hist[tid];
        base[tid] = h ? atomicAdd(&gcnt[tid], h) : 0;
        hist[tid] = 0;   // reuse as local cursor
    }
    __syncthreads();

    for (int i = tid; i < cnt; i += 1024) {
        unsigned v = staged[i];
        int g = v >> 16;
        int pos = base[g] + atomicAdd(&hist[g], 1);
        if (pos < CAP)
            bucket[(size_t)g * CAP + pos] = (unsigned short)(v & 0xFFFFu);
    }
}

// W1 [128][128], W2 [64][128] f32 -> W1T/W2T bf16 transposed; also zeroes gcnt.
__global__ __launch_bounds__(256) void convert_w(const float* __restrict__ W1,
                                                 const float* __restrict__ W2,
                                                 unsigned short* __restrict__ W1T,
                                                 unsigned short* __restrict__ W2T,
                                                 int* gcnt, int G) {
    int stride = gridDim.x * 256;
    int t0 = blockIdx.x * 256 + threadIdx.x;
    for (int i = t0; i < 128 * 128; i += stride) {
        int k = i >> 7, c = i & 127;
        W1T[c * 128 + k] = f2bf(W1[i]);
    }
    for (int i = t0; i < 64 * 128; i += stride) {
        int k = i >> 7, c = i & 127;
        W2T[c * 64 + k] = f2bf(W2[i]);
    }
    for (int i = t0; i < G; i += stride) gcnt[i] = 0;
}

// GEMM phase (16 waves): wave w<14: stripe s=w>>1 (16 rows), head-half h=w&1
// (4 col-tiles). sA [rows][SA] bf16 @ WT (GLOBAL [128 cols][K] bf16, L2) ->
// sHT[col*136+row] bf16 (packed 8B) + per-head logits into sAs/sAd.
// Fragment pattern verified on-device (rounds 8-13).
template <int K, int SA>
__device__ __forceinline__ void gemm_block(const unsigned short* sA,
                                           const unsigned short* __restrict__ WT,
                                           const float* __restrict__ a_src,
                                           const float* __restrict__ a_dst,
                                           unsigned short* sHT,
                                           float* sAs, float* sAd,
                                           int lane, int wave) {
    if (wave >= 14) return;   // 7 stripes x 2 head-halves
    int s = wave >> 1, h = wave & 1;
    int fr = lane & 15, fk = (lane >> 4) * 8;
    f32x4 acc[4];
#pragma unroll
    for (int t = 0; t < 4; ++t) acc[t] = (f32x4){0.f, 0.f, 0.f, 0.f};
#pragma unroll
    for (int ks = 0; ks < K / 32; ++ks) {
        bf16x8 a = *reinterpret_cast<const bf16x8*>(&sA[(s * 16 + fr) * SA + ks * 32 + fk]);
#pragma unroll
        for (int t = 0; t < 4; ++t) {
            bf16x8 b = *reinterpret_cast<const bf16x8*>(
                &WT[((h * 4 + t) * 16 + fr) * K + ks * 32 + fk]);
            acc[t] = __builtin_amdgcn_mfma_f32_16x16x32_bf16(a, b, acc[t], 0, 0, 0);
        }
    }
    int rb = s * 16 + (lane >> 4) * 4;
    float ps[4] = {0, 0, 0, 0}, pd[4] = {0, 0, 0, 0};
#pragma unroll
    for (int t = 0; t < 4; ++t) {
        int col = (h * 4 + t) * 16 + fr;
        float as_ = a_src[col], ad_ = a_dst[col];
        float v0 = acc[t][0], v1 = acc[t][1], v2 = acc[t][2], v3 = acc[t][3];
        ps[0] += v0 * as_; pd[0] += v0 * ad_;
        ps[1] += v1 * as_; pd[1] += v1 * ad_;
        ps[2] += v2 * as_; pd[2] += v2 * ad_;
        ps[3] += v3 * as_; pd[3] += v3 * ad_;
        *reinterpret_cast<uint2*>(&sHT[col * 136 + rb]) =
            make_uint2(cvt_pk(v0, v1), cvt_pk(v2, v3));
    }
#pragma unroll
    for (int off = 1; off <= 8; off <<= 1) {
#pragma unroll
        for (int j = 0; j < 4; ++j) {
            ps[j] += __shfl_xor(ps[j], off);
            pd[j] += __shfl_xor(pd[j], off);
        }
    }
    if (fr == 0) {
#pragma unroll
        for (int j = 0; j < 4; ++j) {
            int d = rb + j;   // up to 111; arrays sized 256
            sAs[d * 2 + h] = ps[j];
            sAd[d * 2 + h] = pd[j];
        }
    }
}

// Aggregation (16 waves, heads sequential): per head {no-max softmax (4-bit
// multiplicity, lane owns sources 2l/2l+1) -> sP packed b32; barrier; MFMA
// 28 tiles in 2 rounds, res += acc/z; barrier}.
__device__ __forceinline__ void agg_heads(unsigned short* sP,
                                          const unsigned short* sHT,
                                          const unsigned* scnt,
                                          const float* sAs, const float* sAd,
                                          float* sRZ, f32x4 res[2],
                                          int lane, int wave) {
    for (int head = 0; head < 2; ++head) {
        for (int d = wave; d < NPG; d += 16) {
            float adh = sAd[d * 2 + head];
            unsigned w = scnt[d * 16 + (lane >> 2)];
            int sh = (lane & 3) * 8;
            unsigned m0 = (w >> sh) & 15u;
            unsigned m1 = (w >> (sh + 4)) & 15u;
            // sAs[4l..4l+3] = {s0.h0, s0.h1, s1.h0, s1.h1}; tail (>=224) zeroed
            float4 a4 = *reinterpret_cast<const float4*>(&sAs[lane * 4]);
            float e0 = (head ? a4.y : a4.x) + adh;
            float e1 = (head ? a4.w : a4.z) + adh;
            // no max-subtraction: |e| <~6 by construction; softmax shift-inv.
            float p0 = m0 ? (float)m0 * __expf(lrelu(e0)) : 0.f;
            float p1 = m1 ? (float)m1 * __expf(lrelu(e1)) : 0.f;
            float z = p0 + p1;
            for (int off = 32; off; off >>= 1) z += __shfl_xor(z, off);
            *reinterpret_cast<unsigned*>(&sP[d * 136 + lane * 2]) = cvt_pk(p0, p1);
            if (lane == 0) sRZ[d] = 1.f / z;
        }
        __syncthreads();
#pragma unroll
        for (int i = 0; i < 2; ++i) {
            int t = wave + 16 * i;
            if (t < 28) {
                int mt = t >> 2, nt = t & 3;
                int arow = mt * 16 + (lane & 15);
                int brow = head * 64 + nt * 16 + (lane & 15);
                int kofs = (lane >> 4) * 8;
                f32x4 acc = (f32x4){0.f, 0.f, 0.f, 0.f};
#pragma unroll
                for (int ks = 0; ks < 4; ++ks) {
                    bf16x8 a = *reinterpret_cast<const bf16x8*>(&sP[arow * 136 + ks * 32 + kofs]);
                    bf16x8 b = *reinterpret_cast<const bf16x8*>(&sHT[brow * 136 + ks * 32 + kofs]);
                    acc = __builtin_amdgcn_mfma_f32_16x16x32_bf16(a, b, acc, 0, 0, 0);
                }
                int dbase = mt * 16 + (lane >> 4) * 4;
#pragma unroll
                for (int r = 0; r < 4; ++r)
                    res[i][r] += acc[r] * sRZ[dbase + r];
            }
        }
        __syncthreads();
    }
}

// One block (1024 thr = 16 waves) per graph: whole network in 75 KB LDS.
__global__ __launch_bounds__(1024, 8) void graph_fused(
    const float* __restrict__ x,
    const unsigned short* __restrict__ W1T,
    const unsigned short* __restrict__ W2T,
    const float* __restrict__ as1, const float* __restrict__ ad1,
    const float* __restrict__ b1,
    const float* __restrict__ as2, const float* __restrict__ ad2,
    const float* __restrict__ b2,
    const float* __restrict__ Wc, const float* __restrict__ bc,
    const int* __restrict__ gcnt, const unsigned short* __restrict__ bucket,
    const int* __restrict__ y,
    float* __restrict__ preds, float* __restrict__ yout) {
    extern __shared__ char smem[];
    unsigned short* sHT  = (unsigned short*)(smem + OFF_HT);
    float*          sOut = (float*)(smem + OFF_HT);            // after agg2
    unsigned short* R3u  = (unsigned short*)(smem + OFF_R3);   // sX -> P1 -> sB -> P2
    unsigned*       scnt = (unsigned*)(smem + OFF_SCNT);
    float*          sAs  = (float*)(smem + OFF_SAS);
    float*          sAd  = (float*)(smem + OFF_SAD);
    float*          sRZ  = (float*)(smem + OFF_SRZ);
    float*          sWc  = (float*)(smem + OFF_SWC);
    float*          sbc  = (float*)(smem + OFF_SBC);

    int g = blockIdx.x, gbase = g * NPG, tid = threadIdx.x;
    int lane = tid & 63, wave = tid >> 6;
    int cnt = min(gcnt[g], CAP);
    float4 z4 = make_float4(0.f, 0.f, 0.f, 0.f);

    // ---- phase A: zero + stage ----
    for (int i = tid; i < 1600; i += 1024) scnt[i] = 0;
    for (int i = tid; i < 2176; i += 1024)                   // zero sHT (34816 B)
        *reinterpret_cast<float4*>((char*)sHT + i * 16) = z4;
    for (int i = tid; i < NPG * 16; i += 1024) {             // x -> sX bf16
        int r = i >> 4, kc = (i & 15) * 8;
        const float* xp = &x[(size_t)(gbase + r) * 128 + kc];
        float4 v0 = *reinterpret_cast<const float4*>(xp);
        float4 v1 = *reinterpret_cast<const float4*>(xp + 4);
        uint4 u = make_uint4(cvt_pk(v0.x, v0.y), cvt_pk(v0.z, v0.w),
                             cvt_pk(v1.x, v1.y), cvt_pk(v1.z, v1.w));
        *reinterpret_cast<uint4*>(&R3u[r * 136 + kc]) = u;
    }
    for (int i = tid; i < 12 * 17; i += 1024) {              // zero sX rows 100..111
        int r = 100 + i / 17, c = (i % 17) * 8;
        *reinterpret_cast<float4*>(&R3u[r * 136 + c]) = z4;
    }
    for (int i = tid; i < 640; i += 1024) sWc[i] = Wc[i];
    if (tid < 10) sbc[tid] = bc[tid];
    if (tid >= 32 && tid < 64) { sAs[192 + tid] = 0.f; sAd[192 + tid] = 0.f; }  // tails 224..255
    if (tid < NPG) yout[gbase + tid] = (float)y[gbase + tid];   // fused ycopy
    __syncthreads();
    for (int i = tid; i < cnt; i += 1024) {                  // edge multiplicities
        unsigned v = bucket[(size_t)g * CAP + i];
        atomicAdd(&scnt[(v >> 8) * 16 + ((v & 255) >> 3)], 1u << ((v & 7) * 4));
    }
    __syncthreads();

    // ---- layer 1: gemm + agg ----
    gemm_block<128, 136>(R3u, W1T, as1, ad1, sHT, sAs, sAd, lane, wave);
    __syncthreads();

    f32x4 res[2];
    res[0] = (f32x4){0.f, 0.f, 0.f, 0.f};
    res[1] = (f32x4){0.f, 0.f, 0.f, 0.f};
    agg_heads(R3u, sHT, scnt, sAs, sAd, sRZ, res, lane, wave);   // P1 over sX

    // epilogue -> sB (bf16 [112][72] at R3, over dead P1): +b1, relu
    {
        unsigned short* sB = R3u;
        int fr = lane & 15;
#pragma unroll
        for (int i = 0; i < 2; ++i) {
            int t = wave + 16 * i;
            if (t < 28) {
                int mt = t >> 2, nt = t & 3;
                int col = nt * 16 + fr;
                float bv = b1[col];
                int d0 = mt * 16 + (lane >> 4) * 4;
                unsigned u01 = cvt_pk(fmaxf(0.5f * res[i][0] + bv, 0.f),
                                      fmaxf(0.5f * res[i][1] + bv, 0.f));
                unsigned u23 = cvt_pk(fmaxf(0.5f * res[i][2] + bv, 0.f),
                                      fmaxf(0.5f * res[i][3] + bv, 0.f));
                if (d0 + 0 < NPG) sB[(d0 + 0) * 72 + col] = (unsigned short)u01;
                if (d0 + 1 < NPG) sB[(d0 + 1) * 72 + col] = (unsigned short)(u01 >> 16);
                if (d0 + 2 < NPG) sB[(d0 + 2) * 72 + col] = (unsigned short)u23;
                if (d0 + 3 < NPG) sB[(d0 + 3) * 72 + col] = (unsigned short)(u23 >> 16);
            }
        }
        for (int i = tid; i < 12 * 9; i += 1024) {           // zero sB rows 100..111
            int r = 100 + i / 9, c = (i % 9) * 8;
            *reinterpret_cast<float4*>(&sB[r * 72 + c]) = z4;
        }
    }
    __syncthreads();

    // ---- layer 2: gemm + agg ----
    gemm_block<64, 72>(R3u, W2T, as2, ad2, sHT, sAs, sAd, lane, wave);
    __syncthreads();

    res[0] = (f32x4){0.f, 0.f, 0.f, 0.f};
    res[1] = (f32x4){0.f, 0.f, 0.f, 0.f};
    agg_heads(R3u, sHT, scnt, sAs, sAd, sRZ, res, lane, wave);   // P2 over sB

    // epilogue -> sOut (f32 [112][68] over dead sHT): +b2, no relu
    {
        int fr = lane & 15;
#pragma unroll
        for (int i = 0; i < 2; ++i) {
            int t = wave + 16 * i;
            if (t < 28) {
                int mt = t >> 2, nt = t & 3;
                int col = nt * 16 + fr;
                float bv = b2[col];
#pragma unroll
                for (int r = 0; r < 4; ++r) {
                    int d = mt * 16 + (lane >> 4) * 4 + r;
                    if (d < NPG) sOut[d * 68 + col] = 0.5f * res[i][r] + bv;
                }
            }
        }
    }
    __syncthreads();

    // ---- classifier (float4 LDS reads, contiguous global stores) ----
    for (int idx = tid; idx < NPG * 10; idx += 1024) {
        int d = idx / 10, j = idx % 10;
        float acc = sbc[j];
#pragma unroll
        for (int c = 0; c < 64; c += 4) {
            float4 h4 = *reinterpret_cast<const float4*>(&sOut[d * 68 + c]);
            acc += h4.x * sWc[(c + 0) * 10 + j];
            acc += h4.y * sWc[(c + 1) * 10 + j];
            acc += h4.z * sWc[(c + 2) * 10 + j];
            acc += h4.w * sWc[(c + 3) * 10 + j];
        }
        preds[(size_t)(gbase + d) * 10 + j] = acc;
    }
}

extern "C" void kernel_launch(void* const* d_in, const int* in_sizes, int n_in,
                              void* d_out, int out_size, void* d_ws, size_t ws_size,
                              hipStream_t stream) {
    const float* x   = (const float*)d_in[0];
    const int*   ei  = (const int*)d_in[1];
    const int*   y   = (const int*)d_in[3];
    const float* W1  = (const float*)d_in[4];
    const float* as1 = (const float*)d_in[5];
    const float* ad1 = (const float*)d_in[6];
    const float* b1  = (const float*)d_in[7];
    const float* W2  = (const float*)d_in[8];
    const float* as2 = (const float*)d_in[9];
    const float* ad2 = (const float*)d_in[10];
    const float* b2  = (const float*)d_in[11];
    const float* Wc  = (const float*)d_in[12];
    const float* bc  = (const float*)d_in[13];

    int n = in_sizes[0] / 128;   // 50000
    int e = in_sizes[1] / 2;     // 850000
    int G = n / NPG;             // 500 graphs
    const int* src = ei;
    const int* dst = ei + e;

    char* ws = (char*)d_ws;
    size_t off = 0;
    auto alloc = [&](size_t bytes) -> void* {
        void* p = ws + off;
        off = (off + bytes + 255) & ~size_t(255);
        return p;
    };
    unsigned short* W1T = (unsigned short*)alloc((size_t)128 * 128 * 2);
    unsigned short* W2T = (unsigned short*)alloc((size_t)128 * 64 * 2);
    int* gcnt = (int*)alloc((size_t)G * 4);
    unsigned short* bucket = (unsigned short*)alloc((size_t)G * CAP * 2);

    float* preds = (float*)d_out;
    float* yout  = preds + (size_t)n * 10;

    int bb = (e + EPB - 1) / EPB;

    // prep: weight convert + gcnt zero, then edge bucketing
    convert_w<<<96, 256, 0, stream>>>(W1, W2, W1T, W2T, gcnt, G);
    bucket2_kernel<<<bb, 1024, 0, stream>>>(src, dst, gcnt, bucket, e);

    // the whole network, one block per graph (2 blocks/CU, 32 waves/CU)
    graph_fused<<<G, 1024, SMEM_BYTES, stream>>>(x, W1T, W2T, as1, ad1, b1,
                                                 as2, ad2, b2, Wc, bc,
                                                 gcnt, bucket, y, preds, yout);
}